// Round 8
// baseline (170.395 us; speedup 1.0000x reference)
//
#include <hip/hip_runtime.h>
#include <math.h>

#define KDIM 128
#define TLEN 512
#define BATCH 16
#define CH_L 16
#define NCH 32           // segments (replay blocks) per batch
#define NMAT 31          // chunk matrices: chunk c covers t in [16c+1, 16c+16]

typedef _Float16 half8 __attribute__((ext_vector_type(8)));
typedef _Float16 half4 __attribute__((ext_vector_type(4)));
typedef _Float16 half2t __attribute__((ext_vector_type(2)));
typedef float floatx4 __attribute__((ext_vector_type(4)));

#if defined(__has_builtin)
#if __has_builtin(__builtin_amdgcn_fdot2)
#define HAVE_FDOT2 1
#endif
#endif

static __device__ __forceinline__ float dot2f(half2t a, half2t b, float c) {
#ifdef HAVE_FDOT2
    return __builtin_amdgcn_fdot2(a, b, c, false);
#else
    return fmaf((float)a[0], (float)b[0], fmaf((float)a[1], (float)b[1], c));
#endif
}

// acc += dot(packed-f16 w (4 VGPRs = 8 halfs), half8 v)
static __device__ __forceinline__ float dot8(const half8 v, const float4 w, float acc) {
    const uint4 r = __builtin_bit_cast(uint4, v);
    acc = dot2f(__builtin_bit_cast(half2t, w.x), __builtin_bit_cast(half2t, r.x), acc);
    acc = dot2f(__builtin_bit_cast(half2t, w.y), __builtin_bit_cast(half2t, r.y), acc);
    acc = dot2f(__builtin_bit_cast(half2t, w.z), __builtin_bit_cast(half2t, r.z), acc);
    acc = dot2f(__builtin_bit_cast(half2t, w.w), __builtin_bit_cast(half2t, r.w), acc);
    return acc;
}

// ---- asm-anchored loads (proven R6, scan only): volatile asm pins issue order
static __device__ __forceinline__ half8 gload16_asm(const _Float16* p) {
    half8 r;
    asm volatile("global_load_dwordx4 %0, %1, off" : "=v"(r) : "v"(p));
    return r;
}
static __device__ __forceinline__ float gload4_asm(const float* p) {
    float r;
    asm volatile("global_load_dword %0, %1, off" : "=v"(r) : "v"(p));
    return r;
}

// ---------------- workspace layout (bytes) ----------------
// PST : f16 [BATCH][NMAT] chunk products; scan layout: 16B unit u = (2K+h)*64+l
//       holds P[enter=K*8+e][exit=2l+h]
// SVEC: f32 [BATCH][NMAT][128] per-enter-column log scales
#define WSN_PST   0
#define WSN_SVEC  16252928
#define WSN_AENT  16506880
#define WSN_NEED  16769024

// Frag conventions (validated):
//  A-frag tile(mt,kt): lane(quad,lm) holds A[mt*16+lm][kt*32+quad*8 .. +8]
//  B-frag tile(kt,nt): lane(quad,lm) holds B[kt*32+quad*8 .. +8][nt*16+lm]
//  C/D  tile(mt,nt):   lane(quad,lm) reg q = C[mt*16+quad*4+q][nt*16+lm]

// ============ kernel 1: TWO chunks per block — A-reads feed 4 MFMAs ===========
// R7 lesson (4th failure): >96 VGPR of loop-invariant state cannot be held on
// this toolchain; the per-iter LDS re-read of F (3.1K cyc/CU-iter) is the
// structural floor of the 1-chunk/block design. F depends ONLY on trans, so
// one block now runs chunk c of batches b and b+8: with ch,nt as the INNER
// MFMA loops each A-read feeds 4 MFMAs (A-traffic per MFMA halves). The 128
// accumulators are MFMA C/D (un-rematerializable -> AGPRs, not subject to the
// arch-VGPR cap); arch-reg live stays ~110-130 (Bf 64 + temps).
// LDS 124,928 B -> 1 block/CU; 248 blocks. XCD note: bid%8 = r keeps batches
// {r, r+8} on XCD r = where scan blocks r and r+8 also land.
__global__ __launch_bounds__(256, 1) void crf_chunkpair(
    const float* __restrict__ trans, const float* __restrict__ em,
    _Float16* __restrict__ Pst, float* __restrict__ Svec)
{
    const int bid = blockIdx.x;
    const int r = bid & 7, c = bid >> 3;      // c in 0..NMAT-1
    const int tid = threadIdx.x;
    const int w = tid >> 6, lane = tid & 63;
    const int quad = lane >> 4, lm = lane & 15;

    __shared__ __align__(16) _Float16 Flds[128 * 136];   // 34,816 B
    __shared__ __align__(16) _Float16 Wscr[4][2][4608];  // 73,728 B
    __shared__ __align__(16) float gAll[2][16 * KDIM];   // 16,384 B

    const int t0 = c * CH_L + 1;
    const float* embs[2] = {em + (size_t)r * TLEN * KDIM,
                            em + (size_t)(r + 8) * TLEN * KDIM};

    // ---- stage F (transposed exp(trans)) ----
    {
        const int m = tid & 127, kh = tid >> 7;
        #pragma unroll
        for (int kk = 0; kk < 8; ++kk) {
            const int k0 = kh * 64 + kk * 8;
            half8 o;
            #pragma unroll
            for (int jj = 0; jj < 8; ++jj)
                o[jj] = (_Float16)__expf(trans[(k0 + jj) * KDIM + m]);
            *(half8*)&Flds[m * 136 + k0] = o;
        }
    }
    // ---- stage g = exp(em rows t0..t0+15) for both chunks ----
    #pragma unroll
    for (int ch = 0; ch < 2; ++ch) {
        const int i8 = tid * 8;
        const float4 e0 = *(const float4*)&embs[ch][t0 * KDIM + i8];
        const float4 e1 = *(const float4*)&embs[ch][t0 * KDIM + i8 + 4];
        float4 g0, g1;
        g0.x = __expf(e0.x); g0.y = __expf(e0.y); g0.z = __expf(e0.z); g0.w = __expf(e0.w);
        g1.x = __expf(e1.x); g1.y = __expf(e1.y); g1.z = __expf(e1.z); g1.w = __expf(e1.w);
        *(float4*)&gAll[ch][i8] = g0;
        *(float4*)&gAll[ch][i8 + 4] = g1;
    }
    __syncthreads();                                     // the ONLY barrier

    float sc[2][2];

    // ---- init B0 = diag(g0)*F cols, column-normalized; STORE to LDS so the
    //      main loop has a uniform read->mfma->write shape ----
    #pragma unroll
    for (int ch = 0; ch < 2; ++ch)
        #pragma unroll
        for (int nt = 0; nt < 2; ++nt) {
            float tv[4][8];
            float cm = 0.f;
            const int n = 32 * w + nt * 16 + lm;
            #pragma unroll
            for (int kt = 0; kt < 4; ++kt) {
                const int r0 = kt * 32 + quad * 8;
                const float4 ga = *(const float4*)&gAll[ch][r0];
                const float4 gb = *(const float4*)&gAll[ch][r0 + 4];
                const float gg[8] = {ga.x, ga.y, ga.z, ga.w, gb.x, gb.y, gb.z, gb.w};
                const float4 ta = *(const float4*)&trans[(size_t)n * KDIM + r0];
                const float4 tb = *(const float4*)&trans[(size_t)n * KDIM + r0 + 4];
                const float tt[8] = {ta.x, ta.y, ta.z, ta.w, tb.x, tb.y, tb.z, tb.w};
                #pragma unroll
                for (int jj = 0; jj < 8; ++jj) {
                    const float v = __expf(tt[jj]) * gg[jj];
                    tv[kt][jj] = v;
                    cm = fmaxf(cm, v);
                }
            }
            cm = fmaxf(cm, __shfl_xor(cm, 16));
            cm = fmaxf(cm, __shfl_xor(cm, 32));
            const float ri = 1.0f / cm;
            sc[ch][nt] = __logf(cm);
            #pragma unroll
            for (int kt = 0; kt < 4; ++kt) {
                half8 o;
                #pragma unroll
                for (int jj = 0; jj < 8; ++jj) o[jj] = (_Float16)(tv[kt][jj] * ri);
                // lane writes exactly the address it reads its B-frag from
                *(half8*)&Wscr[w][ch][lm * 136 + quad * 8 + nt * 2176 + kt * 32] = o;
            }
        }

    const floatx4 z4 = {0.f, 0.f, 0.f, 0.f};
    for (int it = 1; it < 16; ++it) {
        // ---- load all B fragments for this iteration (16 x ds_read_b128) ----
        half8 Bf[2][2][4];
        #pragma unroll
        for (int ch = 0; ch < 2; ++ch)
            #pragma unroll
            for (int nt = 0; nt < 2; ++nt)
                #pragma unroll
                for (int kt = 0; kt < 4; ++kt)
                    Bf[ch][nt][kt] = *(const half8*)
                        &Wscr[w][ch][lm * 136 + quad * 8 + nt * 2176 + kt * 32];

        // ---- MFMA nest: one A-read feeds 4 MFMAs (2ch x 2nt) ----
        floatx4 acc[2][2][8];
        #pragma unroll
        for (int mt = 0; mt < 8; ++mt) {
            const half8 a = *(const half8*)&Flds[lm * 136 + quad * 8 + mt * 2176];
            acc[0][0][mt] = __builtin_amdgcn_mfma_f32_16x16x32_f16(a, Bf[0][0][0], z4, 0, 0, 0);
            acc[0][1][mt] = __builtin_amdgcn_mfma_f32_16x16x32_f16(a, Bf[0][1][0], z4, 0, 0, 0);
            acc[1][0][mt] = __builtin_amdgcn_mfma_f32_16x16x32_f16(a, Bf[1][0][0], z4, 0, 0, 0);
            acc[1][1][mt] = __builtin_amdgcn_mfma_f32_16x16x32_f16(a, Bf[1][1][0], z4, 0, 0, 0);
        }
        #pragma unroll
        for (int kt = 1; kt < 4; ++kt)
            #pragma unroll
            for (int mt = 0; mt < 8; ++mt) {
                const half8 a = *(const half8*)&Flds[lm * 136 + quad * 8 + mt * 2176 + kt * 32];
                acc[0][0][mt] = __builtin_amdgcn_mfma_f32_16x16x32_f16(a, Bf[0][0][kt], acc[0][0][mt], 0, 0, 0);
                acc[0][1][mt] = __builtin_amdgcn_mfma_f32_16x16x32_f16(a, Bf[0][1][kt], acc[0][1][mt], 0, 0, 0);
                acc[1][0][mt] = __builtin_amdgcn_mfma_f32_16x16x32_f16(a, Bf[1][0][kt], acc[1][0][mt], 0, 0, 0);
                acc[1][1][mt] = __builtin_amdgcn_mfma_f32_16x16x32_f16(a, Bf[1][1][kt], acc[1][1][mt], 0, 0, 0);
            }

        // ---- per (ch,nt): row-scale by g_t, column max, rescale, relayout ----
        #pragma unroll
        for (int ch = 0; ch < 2; ++ch)
            #pragma unroll
            for (int nt = 0; nt < 2; ++nt) {
                const float* g = &gAll[ch][it * KDIM];
                float cm = 0.f;
                #pragma unroll
                for (int mt = 0; mt < 8; ++mt) {
                    const float4 gv = *(const float4*)&g[mt * 16 + quad * 4];
                    floatx4 v = acc[ch][nt][mt];
                    v.x *= gv.x; v.y *= gv.y; v.z *= gv.z; v.w *= gv.w;
                    acc[ch][nt][mt] = v;
                    cm = fmaxf(cm, fmaxf(fmaxf(v.x, v.y), fmaxf(v.z, v.w)));
                }
                cm = fmaxf(cm, __shfl_xor(cm, 16));
                cm = fmaxf(cm, __shfl_xor(cm, 32));
                const float ri = 1.0f / cm;
                sc[ch][nt] += __logf(cm);

                _Float16* Wb = &Wscr[w][ch][0];
                if (it < 15) {
                    #pragma unroll
                    for (int mt = 0; mt < 8; ++mt) {
                        const floatx4 v = acc[ch][nt][mt];
                        half4 o;
                        o[0] = (_Float16)(v.x * ri);
                        o[1] = (_Float16)(v.y * ri);
                        o[2] = (_Float16)(v.z * ri);
                        o[3] = (_Float16)(v.w * ri);
                        *(half4*)&Wb[lm * 136 + quad * 4 + nt * 2176 + mt * 16] = o;
                    }
                } else {
                    // final iteration: transposed T[m][n_local], stride 36
                    #pragma unroll
                    for (int mt = 0; mt < 8; ++mt) {
                        const floatx4 v = acc[ch][nt][mt];
                        const int ba = quad * 144 + lm + mt * 576 + nt * 16;
                        Wb[ba]       = (_Float16)(v.x * ri);
                        Wb[ba + 36]  = (_Float16)(v.y * ri);
                        Wb[ba + 72]  = (_Float16)(v.z * ri);
                        Wb[ba + 108] = (_Float16)(v.w * ri);
                    }
                }
            }
    }

    // ---- epilogue per chunk: gather scan-layout 16B units + coalesced store --
    #pragma unroll
    for (int ch = 0; ch < 2; ++ch) {
        const int b = r + 8 * ch;
        _Float16* Wb = &Wscr[w][ch][0];
        _Float16* Pc = Pst + ((size_t)(b * NMAT + c)) * 16384;
        #pragma unroll
        for (int Kl = 0; Kl < 4; ++Kl)
            #pragma unroll
            for (int hh = 0; hh < 2; ++hh) {
                const half4 lo = *(const half4*)&Wb[(2 * lane + hh) * 36 + Kl * 8];
                const half4 hi = *(const half4*)&Wb[(2 * lane + hh) * 36 + Kl * 8 + 4];
                half8 v;
                #pragma unroll
                for (int e = 0; e < 4; ++e) { v[e] = lo[e]; v[4 + e] = hi[e]; }
                const int u = (2 * (4 * w + Kl) + hh) * 64 + lane;
                *(half8*)&Pc[(size_t)u * 8] = v;
            }
        if (quad == 0) {
            float* sp = Svec + ((size_t)(b * NMAT + c)) * KDIM + 32 * w;
            sp[lm] = sc[ch][0];
            sp[lm + 16] = sc[ch][1];
        }
    }
}

// ============ kernel 2: scan with asm-anchored pipelined prefetch (R6) ========
__global__ __launch_bounds__(256, 1) void crf_scanw8(
    const float* __restrict__ em, const _Float16* __restrict__ Pst,
    const float* __restrict__ Svec, float* __restrict__ aEnter)
{
    const int b = blockIdx.x;
    const int tid = threadIdx.x;
    const int w = tid >> 6, lane = tid & 63;

    __shared__ __align__(16) _Float16 pbuf[KDIM];
    __shared__ __align__(16) float part[4][KDIM];
    __shared__ float red[2];

    const _Float16* Pb = Pst + (size_t)b * NMAT * 16384;
    const float* svb = Svec + (size_t)b * NMAT * KDIM;
    float* aeb = aEnter + (size_t)b * NCH * KDIM;
    const int jsv = tid & 127;

    half8 PA[8], PB[8];
    float svA, svB;
    #pragma unroll
    for (int i = 0; i < 8; ++i)
        PA[i] = gload16_asm(&Pb[((8 * w + i) * 64 + lane) * 8]);
    svA = gload4_asm(&svb[jsv]);
    #pragma unroll
    for (int i = 0; i < 8; ++i)
        PB[i] = gload16_asm(&Pb[16384 + ((8 * w + i) * 64 + lane) * 8]);
    svB = gload4_asm(&svb[KDIM + jsv]);

    float lq = 0.f, L = 0.f;
    {
        float a0 = -INFINITY;
        if (tid < KDIM) a0 = em[(size_t)b * TLEN * KDIM + tid];
        float m = a0;
        #pragma unroll
        for (int o = 32; o; o >>= 1) m = fmaxf(m, __shfl_xor(m, o));
        if (w < 2 && lane == 0) red[w] = m;
        __syncthreads();
        const float mx = fmaxf(red[0], red[1]);
        if (tid < KDIM) {
            aeb[tid] = a0;
            lq = a0 - mx;
            L = mx;
        }
        __syncthreads();
    }

    auto STEP = [&](half8 (&P)[8], float& sv, int c) {
        if (c == NMAT - 1) {
            asm volatile("s_waitcnt vmcnt(0)" ::: "memory");
        } else {
            asm volatile("s_waitcnt vmcnt(9)" ::: "memory");
        }
        __builtin_amdgcn_sched_barrier(0);

        if (w < 2) {
            float m = lq + sv;
            #pragma unroll
            for (int o = 32; o; o >>= 1) m = fmaxf(m, __shfl_xor(m, o));
            if (lane == 0) red[w] = m;
        }
        __syncthreads();
        const float M = fmaxf(red[0], red[1]);
        if (w < 2)
            pbuf[tid] = (_Float16)__expf(lq + sv - M);
        __syncthreads();

        float q0 = 0.f, q1 = 0.f;
        #pragma unroll
        for (int kk = 0; kk < 4; ++kk) {
            const float4 wv = *(const float4*)&pbuf[(4 * w + kk) * 8];
            q0 = dot8(P[2 * kk + 0], wv, q0);
            q1 = dot8(P[2 * kk + 1], wv, q1);
        }
        float2 qq; qq.x = q0; qq.y = q1;
        *(float2*)&part[w][2 * lane] = qq;
        __syncthreads();

        if (tid < KDIM) {
            const float q = part[0][tid] + part[1][tid]
                          + part[2][tid] + part[3][tid];
            const float lg = __logf(q);
            aeb[(size_t)(c + 1) * KDIM + tid] = L + M + lg;
            lq = lg;
            L += M;
        }

        if (c + 2 < NMAT) {
            #pragma unroll
            for (int i = 0; i < 8; ++i)
                P[i] = gload16_asm(&Pb[(size_t)(c + 2) * 16384
                                       + ((8 * w + i) * 64 + lane) * 8]);
            sv = gload4_asm(&svb[(size_t)(c + 2) * KDIM + jsv]);
        }
    };

    for (int c = 0; c < NMAT; c += 2) {
        STEP(PA, svA, c);
        if (c + 1 < NMAT) STEP(PB, svB, c + 1);
    }
}

// ============ kernel 3: replay, fallback-structured (R7, passing) =============
__global__ __launch_bounds__(256, 2) void crf_replay3(
    const float* __restrict__ trans, const float* __restrict__ em,
    const int* __restrict__ seq_lens, const float* __restrict__ aEnter,
    float* __restrict__ alpha, float* __restrict__ logZ)
{
    const int c = blockIdx.x, b = blockIdx.y;
    const int tid = threadIdx.x;
    const int j = tid & 127, h = tid >> 7;
    const int lane = tid & 63;

    __shared__ __align__(16) float p_lds[KDIM];
    __shared__ float part[2][KDIM];
    __shared__ float red[8];

    float Ereg[64];
    #pragma unroll
    for (int k = 0; k < 64; ++k)
        Ereg[k] = __expf(trans[(h * 64 + k) * KDIM + j]);

    const int len = seq_lens[b];
    const float* emb = em + (size_t)b * TLEN * KDIM;
    float* outb = alpha + (size_t)b * TLEN * KDIM;

    float a0;
    if (c == 0) a0 = emb[j];
    else        a0 = aEnter[((size_t)b * NCH + c) * KDIM + j];

    {
        float v = a0;
        #pragma unroll
        for (int o = 32; o; o >>= 1) v = fmaxf(v, __shfl_xor(v, o));
        if (lane == 0) red[tid >> 6] = v;
    }
    __syncthreads();
    float L = fmaxf(red[0], red[1]);

    if (h == 0) p_lds[j] = __expf(a0 - L);
    float la = -INFINITY;
    if (c == 0 && h == 0) {
        outb[j] = a0;
        if (len == 1) la = a0;
    }

    const int t_begin = c * CH_L + 1;
    const int t_end = (c == NCH - 1) ? (TLEN - 1) : (c * CH_L + CH_L);

    float ecur = 0.f;
    if (h == 0) ecur = emb[t_begin * KDIM + j];
    __syncthreads();

    for (int t = t_begin; t <= t_end; ++t) {
        float enxt = 0.f;
        if (h == 0 && t < t_end) enxt = emb[(t + 1) * KDIM + j];

        float acc0 = 0.f, acc1 = 0.f, acc2 = 0.f, acc3 = 0.f;
        const float4* p4 = (const float4*)(p_lds + h * 64);
        #pragma unroll
        for (int k4 = 0; k4 < 16; ++k4) {
            const float4 pv = p4[k4];
            acc0 = fmaf(pv.x, Ereg[4 * k4 + 0], acc0);
            acc1 = fmaf(pv.y, Ereg[4 * k4 + 1], acc1);
            acc2 = fmaf(pv.z, Ereg[4 * k4 + 2], acc2);
            acc3 = fmaf(pv.w, Ereg[4 * k4 + 3], acc3);
        }
        part[h][j] = (acc0 + acc1) + (acc2 + acc3);
        __syncthreads();

        if (h == 0) {
            const float q = part[0][j] + part[1][j];
            const float sig = part[0][0] + part[1][0];
            const float A = ecur + L + __logf(q);
            outb[t * KDIM + j] = A;
            if (t == len - 1) la = A;
            p_lds[j] = q * (1.0f / sig) * __expf(ecur);
            L += __logf(sig);
        }
        ecur = enxt;
        __syncthreads();
    }

    const int xown = (len == 1) ? 0 : ((len - 2) >> 4);
    if (c == xown) {
        float m2 = la;
        #pragma unroll
        for (int o = 32; o; o >>= 1) m2 = fmaxf(m2, __shfl_xor(m2, o));
        if (lane == 0) red[tid >> 6] = m2;
        __syncthreads();
        m2 = fmaxf(fmaxf(red[0], red[1]), fmaxf(red[2], red[3]));
        float e = (la == -INFINITY) ? 0.f : __expf(la - m2);
        #pragma unroll
        for (int o = 32; o; o >>= 1) e += __shfl_xor(e, o);
        if (lane == 0) red[4 + (tid >> 6)] = e;
        __syncthreads();
        if (tid == 0)
            logZ[b] = m2 + __logf(red[4] + red[5] + red[6] + red[7]);
    }
}

// ================= fallback (proven R1 kernel) for small ws =================
__global__ __launch_bounds__(256) void crf_forward_fallback(
    const float* __restrict__ trans, const float* __restrict__ em,
    const int* __restrict__ seq_lens, float* __restrict__ alpha_out,
    float* __restrict__ logZ_out)
{
    const int b = blockIdx.x;
    const int tid = threadIdx.x;
    const int j = tid & (KDIM - 1);
    const int h = tid >> 7;

    __shared__ __align__(16) float p_lds[KDIM];
    __shared__ float part[KDIM];
    __shared__ float red[8];

    float Ereg[64];
    #pragma unroll
    for (int k = 0; k < 64; ++k) Ereg[k] = __expf(trans[(h * 64 + k) * KDIM + j]);

    const int len = seq_lens[b];
    const float* emb = em + (size_t)b * TLEN * KDIM;
    float* outb = alpha_out + (size_t)b * TLEN * KDIM;

    float a = 0.f, last_a = 0.f;
    if (h == 0) {
        a = emb[j];
        outb[j] = a;
        if (len == 1) last_a = a;
    }
    for (int t = 1; t < TLEN; ++t) {
        {
            float v = (h == 0) ? a : -INFINITY;
            #pragma unroll
            for (int o = 32; o >= 1; o >>= 1) v = fmaxf(v, __shfl_xor(v, o));
            if ((tid & 63) == 0) red[tid >> 6] = v;
        }
        __syncthreads();
        const float m = fmaxf(red[0], red[1]);
        if (h == 0) p_lds[j] = __expf(a - m);
        __syncthreads();
        float em_t = 0.f;
        if (h == 0) em_t = emb[t * KDIM + j];
        float acc0 = 0.f, acc1 = 0.f, acc2 = 0.f, acc3 = 0.f;
        const float4* p4 = (const float4*)(p_lds + h * 64);
        #pragma unroll
        for (int k4 = 0; k4 < 16; ++k4) {
            float4 pv = p4[k4];
            acc0 = fmaf(pv.x, Ereg[4 * k4 + 0], acc0);
            acc1 = fmaf(pv.y, Ereg[4 * k4 + 1], acc1);
            acc2 = fmaf(pv.z, Ereg[4 * k4 + 2], acc2);
            acc3 = fmaf(pv.w, Ereg[4 * k4 + 3], acc3);
        }
        const float acc = (acc0 + acc1) + (acc2 + acc3);
        if (h == 1) part[j] = acc;
        __syncthreads();
        if (h == 0) {
            const float q = acc + part[j];
            a = em_t + m + __logf(q);
            outb[t * KDIM + j] = a;
            if (t == len - 1) last_a = a;
        }
    }
    {
        float v = (h == 0) ? last_a : -INFINITY;
        #pragma unroll
        for (int o = 32; o >= 1; o >>= 1) v = fmaxf(v, __shfl_xor(v, o));
        if ((tid & 63) == 0) red[tid >> 6] = v;
    }
    __syncthreads();
    const float m2 = fmaxf(red[0], red[1]);
    float e = (h == 0) ? __expf(last_a - m2) : 0.f;
    #pragma unroll
    for (int o = 32; o >= 1; o >>= 1) e += __shfl_xor(e, o);
    if ((tid & 63) == 0) red[4 + (tid >> 6)] = e;
    __syncthreads();
    if (tid == 0) logZ_out[b] = m2 + logf(red[4] + red[5]);
}

extern "C" void kernel_launch(void* const* d_in, const int* in_sizes, int n_in,
                              void* d_out, int out_size, void* d_ws, size_t ws_size,
                              hipStream_t stream) {
    const float* trans    = (const float*)d_in[0];   // K*K
    const float* em       = (const float*)d_in[1];   // B*T*K
    const int*   seq_lens = (const int*)d_in[2];     // B

    float* alpha_out = (float*)d_out;                            // B*T*K
    float* logZ_out  = alpha_out + (size_t)BATCH * TLEN * KDIM;  // B

    char* ws = (char*)d_ws;

    if (ws_size >= (size_t)WSN_NEED) {
        _Float16* Pst  = (_Float16*)(ws + WSN_PST);
        float*    Svec = (float*)(ws + WSN_SVEC);
        float*    aEnt = (float*)(ws + WSN_AENT);
        crf_chunkpair<<<NMAT * 8, 256, 0, stream>>>(trans, em, Pst, Svec);
        crf_scanw8<<<BATCH, 256, 0, stream>>>(em, Pst, Svec, aEnt);
        crf_replay3<<<dim3(NCH, BATCH), 256, 0, stream>>>(trans, em, seq_lens, aEnt,
                                                          alpha_out, logZ_out);
    } else {
        crf_forward_fallback<<<BATCH, 256, 0, stream>>>(trans, em, seq_lens,
                                                        alpha_out, logZ_out);
    }
}

// Round 9
// 147.124 us; speedup vs baseline: 1.1582x; 1.1582x over previous
//
#include <hip/hip_runtime.h>
#include <math.h>

#define KDIM 128
#define TLEN 512
#define BATCH 16
#define CH_L 16
#define NCH 32           // segments (replay blocks) per batch
#define NMAT 31          // chunk matrices: chunk c covers t in [16c+1, 16c+16]

typedef _Float16 half8 __attribute__((ext_vector_type(8)));
typedef _Float16 half4 __attribute__((ext_vector_type(4)));
typedef _Float16 half2t __attribute__((ext_vector_type(2)));
typedef float floatx4 __attribute__((ext_vector_type(4)));

#if defined(__has_builtin)
#if __has_builtin(__builtin_amdgcn_fdot2)
#define HAVE_FDOT2 1
#endif
#endif

static __device__ __forceinline__ float dot2f(half2t a, half2t b, float c) {
#ifdef HAVE_FDOT2
    return __builtin_amdgcn_fdot2(a, b, c, false);
#else
    return fmaf((float)a[0], (float)b[0], fmaf((float)a[1], (float)b[1], c));
#endif
}

// acc += dot(packed-f16 w (4 VGPRs = 8 halfs), half8 v)
static __device__ __forceinline__ float dot8(const half8 v, const float4 w, float acc) {
    const uint4 r = __builtin_bit_cast(uint4, v);
    acc = dot2f(__builtin_bit_cast(half2t, w.x), __builtin_bit_cast(half2t, r.x), acc);
    acc = dot2f(__builtin_bit_cast(half2t, w.y), __builtin_bit_cast(half2t, r.y), acc);
    acc = dot2f(__builtin_bit_cast(half2t, w.z), __builtin_bit_cast(half2t, r.z), acc);
    acc = dot2f(__builtin_bit_cast(half2t, w.w), __builtin_bit_cast(half2t, r.w), acc);
    return acc;
}

// ---- asm-anchored loads (proven R6): volatile asm pins issue order; outputs
// cannot be rematerialized or sunk. Waiting is manual counted s_waitcnt.
static __device__ __forceinline__ half8 gload16_asm(const _Float16* p) {
    half8 r;
    asm volatile("global_load_dwordx4 %0, %1, off" : "=v"(r) : "v"(p));
    return r;
}
static __device__ __forceinline__ float gload4_asm(const float* p) {
    float r;
    asm volatile("global_load_dword %0, %1, off" : "=v"(r) : "v"(p));
    return r;
}

// ---------------- workspace layout (bytes) ----------------
// PST : f16 [BATCH][NMAT] chunk products; scan layout: 16B unit u = (2K+h)*64+l
//       holds P[enter=K*8+e][exit=2l+h]
// SVEC: f32 [BATCH][NMAT][128] per-enter-column log scales
#define WSN_PST   0
#define WSN_SVEC  16252928
#define WSN_AENT  16506880
#define WSN_NEED  16769024

// Frag conventions (validated):
//  A-frag tile(mt,kt): lane(quad,lm) holds A[mt*16+lm][kt*32+quad*8 .. +8]
//  B-frag tile(kt,nt): lane(quad,lm) holds B[kt*32+quad*8 .. +8][nt*16+lm]
//  C/D  tile(mt,nt):   lane(quad,lm) reg q = C[mt*16+quad*4+q][nt*16+lm]

// ============ kernel 1: chunk products (R6-proven, 46us; reverted from R8) ====
// R8 lesson: this kernel is LATENCY-bound — the chunk-pair variant halved
// A-traffic/MFMA but at 1 wave/SIMD ran 1.8x SLOWER. 2 blocks/CU (2 waves/
// SIMD) is the sweet spot; per tiling arithmetic + the >96-VGPR-invariant
// allocator limit (4 failed hoists), ~46us is this decomposition's floor.
__global__ __launch_bounds__(256, 2) void crf_chunkcols2(
    const float* __restrict__ trans, const float* __restrict__ em,
    _Float16* __restrict__ Pst, float* __restrict__ Svec)
{
    const int bid = blockIdx.x;
    const int r = bid & 7, j = bid >> 3;
    const int b = (j < NMAT) ? r : r + 8;
    const int c = (j < NMAT) ? j : j - NMAT;
    const int tid = threadIdx.x;
    const int w = tid >> 6, lane = tid & 63;
    const int quad = lane >> 4, lm = lane & 15;

    __shared__ __align__(16) _Float16 Flds[128 * 136];
    __shared__ __align__(16) _Float16 Wscr[4][4608];
    __shared__ __align__(16) float gAll[16 * KDIM];

    const int t0 = c * CH_L + 1;
    const float* emb = em + (size_t)b * TLEN * KDIM;

    {
        const int m = tid & 127, kh = tid >> 7;
        #pragma unroll
        for (int kk = 0; kk < 8; ++kk) {
            const int k0 = kh * 64 + kk * 8;
            half8 o;
            #pragma unroll
            for (int jj = 0; jj < 8; ++jj)
                o[jj] = (_Float16)__expf(trans[(k0 + jj) * KDIM + m]);
            *(half8*)&Flds[m * 136 + k0] = o;
        }
    }
    {
        const int i8 = tid * 8;
        const float4 e0 = *(const float4*)&emb[t0 * KDIM + i8];
        const float4 e1 = *(const float4*)&emb[t0 * KDIM + i8 + 4];
        float4 g0, g1;
        g0.x = __expf(e0.x); g0.y = __expf(e0.y); g0.z = __expf(e0.z); g0.w = __expf(e0.w);
        g1.x = __expf(e1.x); g1.y = __expf(e1.y); g1.z = __expf(e1.z); g1.w = __expf(e1.w);
        *(float4*)&gAll[i8] = g0;
        *(float4*)&gAll[i8 + 4] = g1;
    }
    __syncthreads();

    _Float16* Wb = Wscr[w];
    float sc[2];
    half8 Bf[4][2];

    #pragma unroll
    for (int nt = 0; nt < 2; ++nt) {
        float tv[4][8];
        float cm = 0.f;
        const int n = 32 * w + nt * 16 + lm;
        #pragma unroll
        for (int kt = 0; kt < 4; ++kt) {
            const int r0 = kt * 32 + quad * 8;
            const float4 ga = *(const float4*)&gAll[r0];
            const float4 gb = *(const float4*)&gAll[r0 + 4];
            const float gg[8] = {ga.x, ga.y, ga.z, ga.w, gb.x, gb.y, gb.z, gb.w};
            const float4 ta = *(const float4*)&trans[(size_t)n * KDIM + r0];
            const float4 tb = *(const float4*)&trans[(size_t)n * KDIM + r0 + 4];
            const float tt[8] = {ta.x, ta.y, ta.z, ta.w, tb.x, tb.y, tb.z, tb.w};
            #pragma unroll
            for (int jj = 0; jj < 8; ++jj) {
                const float v = __expf(tt[jj]) * gg[jj];
                tv[kt][jj] = v;
                cm = fmaxf(cm, v);
            }
        }
        cm = fmaxf(cm, __shfl_xor(cm, 16));
        cm = fmaxf(cm, __shfl_xor(cm, 32));
        const float ri = 1.0f / cm;
        sc[nt] = __logf(cm);
        #pragma unroll
        for (int kt = 0; kt < 4; ++kt)
            #pragma unroll
            for (int jj = 0; jj < 8; ++jj)
                Bf[kt][nt][jj] = (_Float16)(tv[kt][jj] * ri);
    }

    half8 Af[8][4];
    #pragma unroll
    for (int mt = 0; mt < 8; ++mt)
        #pragma unroll
        for (int kt = 0; kt < 4; ++kt)
            Af[mt][kt] = *(const half8*)&Flds[lm * 136 + quad * 8 + mt * 2176 + kt * 32];

    const floatx4 z4 = {0.f, 0.f, 0.f, 0.f};
    for (int it = 1; it < 16; ++it) {
        #pragma unroll
        for (int nt = 0; nt < 2; ++nt) {
            floatx4 acc[8];
            #pragma unroll
            for (int mt = 0; mt < 8; ++mt)
                acc[mt] = __builtin_amdgcn_mfma_f32_16x16x32_f16(Af[mt][0], Bf[0][nt], z4, 0, 0, 0);
            #pragma unroll
            for (int kt = 1; kt < 4; ++kt)
                #pragma unroll
                for (int mt = 0; mt < 8; ++mt)
                    acc[mt] = __builtin_amdgcn_mfma_f32_16x16x32_f16(Af[mt][kt], Bf[kt][nt], acc[mt], 0, 0, 0);

            const float* g = &gAll[it * KDIM];
            float cm = 0.f;
            #pragma unroll
            for (int mt = 0; mt < 8; ++mt) {
                const float4 gv = *(const float4*)&g[mt * 16 + quad * 4];
                floatx4 v = acc[mt];
                v.x *= gv.x; v.y *= gv.y; v.z *= gv.z; v.w *= gv.w;
                acc[mt] = v;
                cm = fmaxf(cm, fmaxf(fmaxf(v.x, v.y), fmaxf(v.z, v.w)));
            }
            cm = fmaxf(cm, __shfl_xor(cm, 16));
            cm = fmaxf(cm, __shfl_xor(cm, 32));
            const float ri = 1.0f / cm;
            sc[nt] += __logf(cm);

            if (it < 15) {
                #pragma unroll
                for (int mt = 0; mt < 8; ++mt) {
                    const floatx4 v = acc[mt];
                    half4 o;
                    o[0] = (_Float16)(v.x * ri);
                    o[1] = (_Float16)(v.y * ri);
                    o[2] = (_Float16)(v.z * ri);
                    o[3] = (_Float16)(v.w * ri);
                    *(half4*)&Wb[lm * 136 + quad * 4 + nt * 2176 + mt * 16] = o;
                }
            } else {
                #pragma unroll
                for (int mt = 0; mt < 8; ++mt) {
                    const floatx4 v = acc[mt];
                    const int ba = quad * 144 + lm + mt * 576 + nt * 16;
                    Wb[ba]       = (_Float16)(v.x * ri);
                    Wb[ba + 36]  = (_Float16)(v.y * ri);
                    Wb[ba + 72]  = (_Float16)(v.z * ri);
                    Wb[ba + 108] = (_Float16)(v.w * ri);
                }
            }
        }
        if (it < 15) {
            #pragma unroll
            for (int kt = 0; kt < 4; ++kt)
                #pragma unroll
                for (int nt = 0; nt < 2; ++nt)
                    Bf[kt][nt] = *(const half8*)&Wb[lm * 136 + quad * 8 + nt * 2176 + kt * 32];
        }
    }

    _Float16* Pc = Pst + ((size_t)(b * NMAT + c)) * 16384;
    #pragma unroll
    for (int Kl = 0; Kl < 4; ++Kl)
        #pragma unroll
        for (int hh = 0; hh < 2; ++hh) {
            const half4 lo = *(const half4*)&Wb[(2 * lane + hh) * 36 + Kl * 8];
            const half4 hi = *(const half4*)&Wb[(2 * lane + hh) * 36 + Kl * 8 + 4];
            half8 v;
            #pragma unroll
            for (int e = 0; e < 4; ++e) { v[e] = lo[e]; v[4 + e] = hi[e]; }
            const int u = (2 * (4 * w + Kl) + hh) * 64 + lane;
            *(half8*)&Pc[(size_t)u * 8] = v;
        }
    if (quad == 0) {
        float* sp = Svec + ((size_t)(b * NMAT + c)) * KDIM + 32 * w;
        sp[lm] = sc[0];
        sp[lm + 16] = sc[1];
    }
}

// ============ kernel 2: scan, DEPTH-3 pipeline + store-aware vmcnt counts =====
// R8 audit: R6's vmcnt(9) forgot the in-loop aeb store -> every step ALSO
// waited for the previous step's global store to retire (~200-500cy serial
// add), and depth-2 gave only ~1 step of load slack (< HBM latency if the
// XCD-L2 gamble misses). Depth 3 (~2 steps slack) + exact counts:
// steady outstanding after G_c = S(1)+G_{c+1}(9)+S(1)+G_{c+2}(9) = 20.
// Waits: vmcnt(20) steady, vmcnt(11) at c=NMAT-2, vmcnt(0) at c=NMAT-1.
// Buffers named PA/PB/PC (rule #20); chunk k lives in buffer k%3.
__global__ __launch_bounds__(256, 1) void crf_scanw9(
    const float* __restrict__ em, const _Float16* __restrict__ Pst,
    const float* __restrict__ Svec, float* __restrict__ aEnter)
{
    const int b = blockIdx.x;
    const int tid = threadIdx.x;
    const int w = tid >> 6, lane = tid & 63;

    __shared__ __align__(16) _Float16 pbuf[KDIM];   // p~ (f16, by enter index)
    __shared__ __align__(16) float part[4][KDIM];   // per-wave matvec partials
    __shared__ float red[2];

    const _Float16* Pb = Pst + (size_t)b * NMAT * 16384;
    const float* svb = Svec + (size_t)b * NMAT * KDIM;
    float* aeb = aEnter + (size_t)b * NCH * KDIM;
    const int jsv = tid & 127;

    // prologue: groups G(0), G(1), G(2) — 9 asm ops each
    half8 PA[8], PB[8], PC[8];
    float svA, svB, svC;
    #pragma unroll
    for (int i = 0; i < 8; ++i)
        PA[i] = gload16_asm(&Pb[((8 * w + i) * 64 + lane) * 8]);
    svA = gload4_asm(&svb[jsv]);
    #pragma unroll
    for (int i = 0; i < 8; ++i)
        PB[i] = gload16_asm(&Pb[16384 + ((8 * w + i) * 64 + lane) * 8]);
    svB = gload4_asm(&svb[KDIM + jsv]);
    #pragma unroll
    for (int i = 0; i < 8; ++i)
        PC[i] = gload16_asm(&Pb[32768 + ((8 * w + i) * 64 + lane) * 8]);
    svC = gload4_asm(&svb[2 * KDIM + jsv]);

    // init state: threads 0..127 own exit/enter column j = tid
    float lq = 0.f, L = 0.f;
    {
        float a0 = -INFINITY;
        if (tid < KDIM) a0 = em[(size_t)b * TLEN * KDIM + tid];
        float m = a0;
        #pragma unroll
        for (int o = 32; o; o >>= 1) m = fmaxf(m, __shfl_xor(m, o));
        if (w < 2 && lane == 0) red[w] = m;
        __syncthreads();
        const float mx = fmaxf(red[0], red[1]);
        if (tid < KDIM) {
            aeb[tid] = a0;
            lq = a0 - mx;
            L = mx;
        }
        __syncthreads();
    }

    auto STEP = [&](half8 (&P)[8], float& sv, int c) {
        // wait: chunk c's group retired; up to 2 newer groups + 2 stores stay
        if (c == NMAT - 1) {
            asm volatile("s_waitcnt vmcnt(0)" ::: "memory");
        } else if (c == NMAT - 2) {
            asm volatile("s_waitcnt vmcnt(11)" ::: "memory");
        } else {
            asm volatile("s_waitcnt vmcnt(20)" ::: "memory");
        }
        __builtin_amdgcn_sched_barrier(0);

        // --- phase A: block max of (lq+sv); p~ into pbuf ---
        if (w < 2) {
            float m = lq + sv;
            #pragma unroll
            for (int o = 32; o; o >>= 1) m = fmaxf(m, __shfl_xor(m, o));
            if (lane == 0) red[w] = m;
        }
        __syncthreads();
        const float M = fmaxf(red[0], red[1]);
        if (w < 2)
            pbuf[tid] = (_Float16)__expf(lq + sv - M);
        __syncthreads();

        // --- phase B: matvec partials; wave w covers enters 32w..32w+32 ---
        float q0 = 0.f, q1 = 0.f;
        #pragma unroll
        for (int kk = 0; kk < 4; ++kk) {
            const float4 wv = *(const float4*)&pbuf[(4 * w + kk) * 8];
            q0 = dot8(P[2 * kk + 0], wv, q0);
            q1 = dot8(P[2 * kk + 1], wv, q1);
        }
        float2 qq; qq.x = q0; qq.y = q1;
        *(float2*)&part[w][2 * lane] = qq;
        __syncthreads();

        // --- phase C: combine, log, emit, advance state ---
        if (tid < KDIM) {
            const float q = part[0][tid] + part[1][tid]
                          + part[2][tid] + part[3][tid];
            const float lg = __logf(q);
            aeb[(size_t)(c + 1) * KDIM + tid] = L + M + lg;
            lq = lg;
            L += M;
        }

        // --- issue group G(c+3) into the just-consumed buffer ---
        if (c + 3 < NMAT) {
            #pragma unroll
            for (int i = 0; i < 8; ++i)
                P[i] = gload16_asm(&Pb[(size_t)(c + 3) * 16384
                                       + ((8 * w + i) * 64 + lane) * 8]);
            sv = gload4_asm(&svb[(size_t)(c + 3) * KDIM + jsv]);
        }
    };

    for (int c = 0; c < NMAT; c += 3) {
        STEP(PA, svA, c);
        if (c + 1 < NMAT) STEP(PB, svB, c + 1);
        if (c + 2 < NMAT) STEP(PC, svC, c + 2);
    }
}

// ============ kernel 3: replay, fallback-structured (R7/R8 proven) ============
__global__ __launch_bounds__(256, 2) void crf_replay3(
    const float* __restrict__ trans, const float* __restrict__ em,
    const int* __restrict__ seq_lens, const float* __restrict__ aEnter,
    float* __restrict__ alpha, float* __restrict__ logZ)
{
    const int c = blockIdx.x, b = blockIdx.y;
    const int tid = threadIdx.x;
    const int j = tid & 127, h = tid >> 7;
    const int lane = tid & 63;

    __shared__ __align__(16) float p_lds[KDIM];
    __shared__ float part[2][KDIM];
    __shared__ float red[8];

    float Ereg[64];
    #pragma unroll
    for (int k = 0; k < 64; ++k)
        Ereg[k] = __expf(trans[(h * 64 + k) * KDIM + j]);

    const int len = seq_lens[b];
    const float* emb = em + (size_t)b * TLEN * KDIM;
    float* outb = alpha + (size_t)b * TLEN * KDIM;

    float a0;
    if (c == 0) a0 = emb[j];
    else        a0 = aEnter[((size_t)b * NCH + c) * KDIM + j];

    {
        float v = a0;
        #pragma unroll
        for (int o = 32; o; o >>= 1) v = fmaxf(v, __shfl_xor(v, o));
        if (lane == 0) red[tid >> 6] = v;
    }
    __syncthreads();
    float L = fmaxf(red[0], red[1]);

    if (h == 0) p_lds[j] = __expf(a0 - L);
    float la = -INFINITY;
    if (c == 0 && h == 0) {
        outb[j] = a0;
        if (len == 1) la = a0;
    }

    const int t_begin = c * CH_L + 1;
    const int t_end = (c == NCH - 1) ? (TLEN - 1) : (c * CH_L + CH_L);

    float ecur = 0.f;
    if (h == 0) ecur = emb[t_begin * KDIM + j];
    __syncthreads();

    for (int t = t_begin; t <= t_end; ++t) {
        float enxt = 0.f;
        if (h == 0 && t < t_end) enxt = emb[(t + 1) * KDIM + j];

        float acc0 = 0.f, acc1 = 0.f, acc2 = 0.f, acc3 = 0.f;
        const float4* p4 = (const float4*)(p_lds + h * 64);
        #pragma unroll
        for (int k4 = 0; k4 < 16; ++k4) {
            const float4 pv = p4[k4];
            acc0 = fmaf(pv.x, Ereg[4 * k4 + 0], acc0);
            acc1 = fmaf(pv.y, Ereg[4 * k4 + 1], acc1);
            acc2 = fmaf(pv.z, Ereg[4 * k4 + 2], acc2);
            acc3 = fmaf(pv.w, Ereg[4 * k4 + 3], acc3);
        }
        part[h][j] = (acc0 + acc1) + (acc2 + acc3);
        __syncthreads();

        if (h == 0) {
            const float q = part[0][j] + part[1][j];
            const float sig = part[0][0] + part[1][0];
            const float A = ecur + L + __logf(q);
            outb[t * KDIM + j] = A;
            if (t == len - 1) la = A;
            p_lds[j] = q * (1.0f / sig) * __expf(ecur);
            L += __logf(sig);
        }
        ecur = enxt;
        __syncthreads();
    }

    const int xown = (len == 1) ? 0 : ((len - 2) >> 4);
    if (c == xown) {
        float m2 = la;
        #pragma unroll
        for (int o = 32; o; o >>= 1) m2 = fmaxf(m2, __shfl_xor(m2, o));
        if (lane == 0) red[tid >> 6] = m2;
        __syncthreads();
        m2 = fmaxf(fmaxf(red[0], red[1]), fmaxf(red[2], red[3]));
        float e = (la == -INFINITY) ? 0.f : __expf(la - m2);
        #pragma unroll
        for (int o = 32; o; o >>= 1) e += __shfl_xor(e, o);
        if (lane == 0) red[4 + (tid >> 6)] = e;
        __syncthreads();
        if (tid == 0)
            logZ[b] = m2 + __logf(red[4] + red[5] + red[6] + red[7]);
    }
}

// ================= fallback (proven R1 kernel) for small ws =================
__global__ __launch_bounds__(256) void crf_forward_fallback(
    const float* __restrict__ trans, const float* __restrict__ em,
    const int* __restrict__ seq_lens, float* __restrict__ alpha_out,
    float* __restrict__ logZ_out)
{
    const int b = blockIdx.x;
    const int tid = threadIdx.x;
    const int j = tid & (KDIM - 1);
    const int h = tid >> 7;

    __shared__ __align__(16) float p_lds[KDIM];
    __shared__ float part[KDIM];
    __shared__ float red[8];

    float Ereg[64];
    #pragma unroll
    for (int k = 0; k < 64; ++k) Ereg[k] = __expf(trans[(h * 64 + k) * KDIM + j]);

    const int len = seq_lens[b];
    const float* emb = em + (size_t)b * TLEN * KDIM;
    float* outb = alpha_out + (size_t)b * TLEN * KDIM;

    float a = 0.f, last_a = 0.f;
    if (h == 0) {
        a = emb[j];
        outb[j] = a;
        if (len == 1) last_a = a;
    }
    for (int t = 1; t < TLEN; ++t) {
        {
            float v = (h == 0) ? a : -INFINITY;
            #pragma unroll
            for (int o = 32; o >= 1; o >>= 1) v = fmaxf(v, __shfl_xor(v, o));
            if ((tid & 63) == 0) red[tid >> 6] = v;
        }
        __syncthreads();
        const float m = fmaxf(red[0], red[1]);
        if (h == 0) p_lds[j] = __expf(a - m);
        __syncthreads();
        float em_t = 0.f;
        if (h == 0) em_t = emb[t * KDIM + j];
        float acc0 = 0.f, acc1 = 0.f, acc2 = 0.f, acc3 = 0.f;
        const float4* p4 = (const float4*)(p_lds + h * 64);
        #pragma unroll
        for (int k4 = 0; k4 < 16; ++k4) {
            float4 pv = p4[k4];
            acc0 = fmaf(pv.x, Ereg[4 * k4 + 0], acc0);
            acc1 = fmaf(pv.y, Ereg[4 * k4 + 1], acc1);
            acc2 = fmaf(pv.z, Ereg[4 * k4 + 2], acc2);
            acc3 = fmaf(pv.w, Ereg[4 * k4 + 3], acc3);
        }
        const float acc = (acc0 + acc1) + (acc2 + acc3);
        if (h == 1) part[j] = acc;
        __syncthreads();
        if (h == 0) {
            const float q = acc + part[j];
            a = em_t + m + __logf(q);
            outb[t * KDIM + j] = a;
            if (t == len - 1) last_a = a;
        }
    }
    {
        float v = (h == 0) ? last_a : -INFINITY;
        #pragma unroll
        for (int o = 32; o >= 1; o >>= 1) v = fmaxf(v, __shfl_xor(v, o));
        if ((tid & 63) == 0) red[tid >> 6] = v;
    }
    __syncthreads();
    const float m2 = fmaxf(red[0], red[1]);
    float e = (h == 0) ? __expf(last_a - m2) : 0.f;
    #pragma unroll
    for (int o = 32; o >= 1; o >>= 1) e += __shfl_xor(e, o);
    if ((tid & 63) == 0) red[4 + (tid >> 6)] = e;
    __syncthreads();
    if (tid == 0) logZ_out[b] = m2 + logf(red[4] + red[5]);
}

extern "C" void kernel_launch(void* const* d_in, const int* in_sizes, int n_in,
                              void* d_out, int out_size, void* d_ws, size_t ws_size,
                              hipStream_t stream) {
    const float* trans    = (const float*)d_in[0];   // K*K
    const float* em       = (const float*)d_in[1];   // B*T*K
    const int*   seq_lens = (const int*)d_in[2];     // B

    float* alpha_out = (float*)d_out;                            // B*T*K
    float* logZ_out  = alpha_out + (size_t)BATCH * TLEN * KDIM;  // B

    char* ws = (char*)d_ws;

    if (ws_size >= (size_t)WSN_NEED) {
        _Float16* Pst  = (_Float16*)(ws + WSN_PST);
        float*    Svec = (float*)(ws + WSN_SVEC);
        float*    aEnt = (float*)(ws + WSN_AENT);
        crf_chunkcols2<<<NMAT * BATCH, 256, 0, stream>>>(trans, em, Pst, Svec);
        crf_scanw9<<<BATCH, 256, 0, stream>>>(em, Pst, Svec, aEnt);
        crf_replay3<<<dim3(NCH, BATCH), 256, 0, stream>>>(trans, em, seq_lens, aEnt,
                                                          alpha_out, logZ_out);
    } else {
        crf_forward_fallback<<<BATCH, 256, 0, stream>>>(trans, em, seq_lens,
                                                        alpha_out, logZ_out);
    }
}

// Round 10
// 141.909 us; speedup vs baseline: 1.2007x; 1.0367x over previous
//
#include <hip/hip_runtime.h>
#include <math.h>

#define KDIM 128
#define TLEN 512
#define BATCH 16
#define CH_L 16
#define NCH 32           // segments (replay blocks) per batch
#define NMAT 31          // chunk matrices: chunk c covers t in [16c+1, 16c+16]

typedef _Float16 half8 __attribute__((ext_vector_type(8)));
typedef _Float16 half4 __attribute__((ext_vector_type(4)));
typedef _Float16 half2t __attribute__((ext_vector_type(2)));
typedef float floatx4 __attribute__((ext_vector_type(4)));

#if defined(__has_builtin)
#if __has_builtin(__builtin_amdgcn_fdot2)
#define HAVE_FDOT2 1
#endif
#endif

static __device__ __forceinline__ float dot2f(half2t a, half2t b, float c) {
#ifdef HAVE_FDOT2
    return __builtin_amdgcn_fdot2(a, b, c, false);
#else
    return fmaf((float)a[0], (float)b[0], fmaf((float)a[1], (float)b[1], c));
#endif
}

// acc += dot(packed-f16 w (4 VGPRs = 8 halfs), half8 v)
static __device__ __forceinline__ float dot8(const half8 v, const float4 w, float acc) {
    const uint4 r = __builtin_bit_cast(uint4, v);
    acc = dot2f(__builtin_bit_cast(half2t, w.x), __builtin_bit_cast(half2t, r.x), acc);
    acc = dot2f(__builtin_bit_cast(half2t, w.y), __builtin_bit_cast(half2t, r.y), acc);
    acc = dot2f(__builtin_bit_cast(half2t, w.z), __builtin_bit_cast(half2t, r.z), acc);
    acc = dot2f(__builtin_bit_cast(half2t, w.w), __builtin_bit_cast(half2t, r.w), acc);
    return acc;
}

// ---- asm-anchored loads (proven R6): volatile asm pins issue order; outputs
// cannot be rematerialized or sunk. Waiting is manual counted s_waitcnt.
static __device__ __forceinline__ half8 gload16_asm(const _Float16* p) {
    half8 r;
    asm volatile("global_load_dwordx4 %0, %1, off" : "=v"(r) : "v"(p));
    return r;
}
static __device__ __forceinline__ float gload4_asm(const float* p) {
    float r;
    asm volatile("global_load_dword %0, %1, off" : "=v"(r) : "v"(p));
    return r;
}

// ---------------- workspace layout (bytes) ----------------
// PST : f16 [BATCH][NMAT] chunk products; scan layout: 16B unit u = (2K+h)*64+l
//       holds P[enter=K*8+e][exit=2l+h]
// SVEC: f32 [BATCH][NMAT][128] per-enter-column log scales
#define WSN_PST   0
#define WSN_SVEC  16252928
#define WSN_AENT  16506880
#define WSN_NEED  16769024

// Frag conventions (validated):
//  A-frag tile(mt,kt): lane(quad,lm) holds A[mt*16+lm][kt*32+quad*8 .. +8]
//  B-frag tile(kt,nt): lane(quad,lm) holds B[kt*32+quad*8 .. +8][nt*16+lm]
//  C/D  tile(mt,nt):   lane(quad,lm) reg q = C[mt*16+quad*4+q][nt*16+lm]

// ============ kernel 1: chunk products (R6 structure + R10 micro-polish) ======
// Structural floor evidence: latency-bound (R8: less traffic at 1 wave/SIMD ->
// 1.8x slower); >96-VGPR invariants unholdable (4 failed hoists); A-to-global
// trades 69TB/s LDS for ~35TB/s L1/L2 (computed net-negative). R10 polish:
//  * hoist the row-scale g reads (identical across nt) -> 8 fewer LDS b128/iter
//  * raw v_rcp (__builtin_amdgcn_rcpf) for the rescale reciprocal — result is
//    rounded to f16 anyway; saves the Newton-refine VALU on the critical path.
__global__ __launch_bounds__(256, 2) void crf_chunkcols6(
    const float* __restrict__ trans, const float* __restrict__ em,
    _Float16* __restrict__ Pst, float* __restrict__ Svec)
{
    const int bid = blockIdx.x;
    const int r = bid & 7, j = bid >> 3;
    const int b = (j < NMAT) ? r : r + 8;
    const int c = (j < NMAT) ? j : j - NMAT;
    const int tid = threadIdx.x;
    const int w = tid >> 6, lane = tid & 63;
    const int quad = lane >> 4, lm = lane & 15;

    __shared__ __align__(16) _Float16 Flds[128 * 136];
    __shared__ __align__(16) _Float16 Wscr[4][4608];
    __shared__ __align__(16) float gAll[16 * KDIM];

    const int t0 = c * CH_L + 1;
    const float* emb = em + (size_t)b * TLEN * KDIM;

    {
        const int m = tid & 127, kh = tid >> 7;
        #pragma unroll
        for (int kk = 0; kk < 8; ++kk) {
            const int k0 = kh * 64 + kk * 8;
            half8 o;
            #pragma unroll
            for (int jj = 0; jj < 8; ++jj)
                o[jj] = (_Float16)__expf(trans[(k0 + jj) * KDIM + m]);
            *(half8*)&Flds[m * 136 + k0] = o;
        }
    }
    {
        const int i8 = tid * 8;
        const float4 e0 = *(const float4*)&emb[t0 * KDIM + i8];
        const float4 e1 = *(const float4*)&emb[t0 * KDIM + i8 + 4];
        float4 g0, g1;
        g0.x = __expf(e0.x); g0.y = __expf(e0.y); g0.z = __expf(e0.z); g0.w = __expf(e0.w);
        g1.x = __expf(e1.x); g1.y = __expf(e1.y); g1.z = __expf(e1.z); g1.w = __expf(e1.w);
        *(float4*)&gAll[i8] = g0;
        *(float4*)&gAll[i8 + 4] = g1;
    }
    __syncthreads();

    _Float16* Wb = Wscr[w];
    float sc[2];
    half8 Bf[4][2];

    #pragma unroll
    for (int nt = 0; nt < 2; ++nt) {
        float tv[4][8];
        float cm = 0.f;
        const int n = 32 * w + nt * 16 + lm;
        #pragma unroll
        for (int kt = 0; kt < 4; ++kt) {
            const int r0 = kt * 32 + quad * 8;
            const float4 ga = *(const float4*)&gAll[r0];
            const float4 gb = *(const float4*)&gAll[r0 + 4];
            const float gg[8] = {ga.x, ga.y, ga.z, ga.w, gb.x, gb.y, gb.z, gb.w};
            const float4 ta = *(const float4*)&trans[(size_t)n * KDIM + r0];
            const float4 tb = *(const float4*)&trans[(size_t)n * KDIM + r0 + 4];
            const float tt[8] = {ta.x, ta.y, ta.z, ta.w, tb.x, tb.y, tb.z, tb.w};
            #pragma unroll
            for (int jj = 0; jj < 8; ++jj) {
                const float v = __expf(tt[jj]) * gg[jj];
                tv[kt][jj] = v;
                cm = fmaxf(cm, v);
            }
        }
        cm = fmaxf(cm, __shfl_xor(cm, 16));
        cm = fmaxf(cm, __shfl_xor(cm, 32));
        const float ri = __builtin_amdgcn_rcpf(cm);
        sc[nt] = __logf(cm);
        #pragma unroll
        for (int kt = 0; kt < 4; ++kt)
            #pragma unroll
            for (int jj = 0; jj < 8; ++jj)
                Bf[kt][nt][jj] = (_Float16)(tv[kt][jj] * ri);
    }

    half8 Af[8][4];
    #pragma unroll
    for (int mt = 0; mt < 8; ++mt)
        #pragma unroll
        for (int kt = 0; kt < 4; ++kt)
            Af[mt][kt] = *(const half8*)&Flds[lm * 136 + quad * 8 + mt * 2176 + kt * 32];

    const floatx4 z4 = {0.f, 0.f, 0.f, 0.f};
    for (int it = 1; it < 16; ++it) {
        // hoisted row-scale factors: identical for both nt passes (R10)
        const float* g = &gAll[it * KDIM];
        float4 gv[8];
        #pragma unroll
        for (int mt = 0; mt < 8; ++mt)
            gv[mt] = *(const float4*)&g[mt * 16 + quad * 4];

        #pragma unroll
        for (int nt = 0; nt < 2; ++nt) {
            floatx4 acc[8];
            #pragma unroll
            for (int mt = 0; mt < 8; ++mt)
                acc[mt] = __builtin_amdgcn_mfma_f32_16x16x32_f16(Af[mt][0], Bf[0][nt], z4, 0, 0, 0);
            #pragma unroll
            for (int kt = 1; kt < 4; ++kt)
                #pragma unroll
                for (int mt = 0; mt < 8; ++mt)
                    acc[mt] = __builtin_amdgcn_mfma_f32_16x16x32_f16(Af[mt][kt], Bf[kt][nt], acc[mt], 0, 0, 0);

            float cm = 0.f;
            #pragma unroll
            for (int mt = 0; mt < 8; ++mt) {
                floatx4 v = acc[mt];
                v.x *= gv[mt].x; v.y *= gv[mt].y; v.z *= gv[mt].z; v.w *= gv[mt].w;
                acc[mt] = v;
                cm = fmaxf(cm, fmaxf(fmaxf(v.x, v.y), fmaxf(v.z, v.w)));
            }
            cm = fmaxf(cm, __shfl_xor(cm, 16));
            cm = fmaxf(cm, __shfl_xor(cm, 32));
            const float ri = __builtin_amdgcn_rcpf(cm);
            sc[nt] += __logf(cm);

            if (it < 15) {
                #pragma unroll
                for (int mt = 0; mt < 8; ++mt) {
                    const floatx4 v = acc[mt];
                    half4 o;
                    o[0] = (_Float16)(v.x * ri);
                    o[1] = (_Float16)(v.y * ri);
                    o[2] = (_Float16)(v.z * ri);
                    o[3] = (_Float16)(v.w * ri);
                    *(half4*)&Wb[lm * 136 + quad * 4 + nt * 2176 + mt * 16] = o;
                }
            } else {
                #pragma unroll
                for (int mt = 0; mt < 8; ++mt) {
                    const floatx4 v = acc[mt];
                    const int ba = quad * 144 + lm + mt * 576 + nt * 16;
                    Wb[ba]       = (_Float16)(v.x * ri);
                    Wb[ba + 36]  = (_Float16)(v.y * ri);
                    Wb[ba + 72]  = (_Float16)(v.z * ri);
                    Wb[ba + 108] = (_Float16)(v.w * ri);
                }
            }
        }
        if (it < 15) {
            #pragma unroll
            for (int kt = 0; kt < 4; ++kt)
                #pragma unroll
                for (int nt = 0; nt < 2; ++nt)
                    Bf[kt][nt] = *(const half8*)&Wb[lm * 136 + quad * 8 + nt * 2176 + kt * 32];
        }
    }

    _Float16* Pc = Pst + ((size_t)(b * NMAT + c)) * 16384;
    #pragma unroll
    for (int Kl = 0; Kl < 4; ++Kl)
        #pragma unroll
        for (int hh = 0; hh < 2; ++hh) {
            const half4 lo = *(const half4*)&Wb[(2 * lane + hh) * 36 + Kl * 8];
            const half4 hi = *(const half4*)&Wb[(2 * lane + hh) * 36 + Kl * 8 + 4];
            half8 v;
            #pragma unroll
            for (int e = 0; e < 4; ++e) { v[e] = lo[e]; v[4 + e] = hi[e]; }
            const int u = (2 * (4 * w + Kl) + hh) * 64 + lane;
            *(half8*)&Pc[(size_t)u * 8] = v;
        }
    if (quad == 0) {
        float* sp = Svec + ((size_t)(b * NMAT + c)) * KDIM + 32 * w;
        sp[lm] = sc[0];
        sp[lm + 16] = sc[1];
    }
}

// ============ kernel 2: scan, DEPTH-3 pipeline + store-aware vmcnt (R9) =======
// Steady outstanding after G_c = S(1)+G_{c+1}(9)+S(1)+G_{c+2}(9) = 20.
// Waits: vmcnt(20) steady, vmcnt(11) at c=NMAT-2, vmcnt(0) at c=NMAT-1.
__global__ __launch_bounds__(256, 1) void crf_scanw9(
    const float* __restrict__ em, const _Float16* __restrict__ Pst,
    const float* __restrict__ Svec, float* __restrict__ aEnter)
{
    const int b = blockIdx.x;
    const int tid = threadIdx.x;
    const int w = tid >> 6, lane = tid & 63;

    __shared__ __align__(16) _Float16 pbuf[KDIM];   // p~ (f16, by enter index)
    __shared__ __align__(16) float part[4][KDIM];   // per-wave matvec partials
    __shared__ float red[2];

    const _Float16* Pb = Pst + (size_t)b * NMAT * 16384;
    const float* svb = Svec + (size_t)b * NMAT * KDIM;
    float* aeb = aEnter + (size_t)b * NCH * KDIM;
    const int jsv = tid & 127;

    // prologue: groups G(0), G(1), G(2) — 9 asm ops each
    half8 PA[8], PB[8], PC[8];
    float svA, svB, svC;
    #pragma unroll
    for (int i = 0; i < 8; ++i)
        PA[i] = gload16_asm(&Pb[((8 * w + i) * 64 + lane) * 8]);
    svA = gload4_asm(&svb[jsv]);
    #pragma unroll
    for (int i = 0; i < 8; ++i)
        PB[i] = gload16_asm(&Pb[16384 + ((8 * w + i) * 64 + lane) * 8]);
    svB = gload4_asm(&svb[KDIM + jsv]);
    #pragma unroll
    for (int i = 0; i < 8; ++i)
        PC[i] = gload16_asm(&Pb[32768 + ((8 * w + i) * 64 + lane) * 8]);
    svC = gload4_asm(&svb[2 * KDIM + jsv]);

    // init state: threads 0..127 own exit/enter column j = tid
    float lq = 0.f, L = 0.f;
    {
        float a0 = -INFINITY;
        if (tid < KDIM) a0 = em[(size_t)b * TLEN * KDIM + tid];
        float m = a0;
        #pragma unroll
        for (int o = 32; o; o >>= 1) m = fmaxf(m, __shfl_xor(m, o));
        if (w < 2 && lane == 0) red[w] = m;
        __syncthreads();
        const float mx = fmaxf(red[0], red[1]);
        if (tid < KDIM) {
            aeb[tid] = a0;
            lq = a0 - mx;
            L = mx;
        }
        __syncthreads();
    }

    auto STEP = [&](half8 (&P)[8], float& sv, int c) {
        // wait: chunk c's group retired; up to 2 newer groups + 2 stores stay
        if (c == NMAT - 1) {
            asm volatile("s_waitcnt vmcnt(0)" ::: "memory");
        } else if (c == NMAT - 2) {
            asm volatile("s_waitcnt vmcnt(11)" ::: "memory");
        } else {
            asm volatile("s_waitcnt vmcnt(20)" ::: "memory");
        }
        __builtin_amdgcn_sched_barrier(0);

        // --- phase A: block max of (lq+sv); p~ into pbuf ---
        if (w < 2) {
            float m = lq + sv;
            #pragma unroll
            for (int o = 32; o; o >>= 1) m = fmaxf(m, __shfl_xor(m, o));
            if (lane == 0) red[w] = m;
        }
        __syncthreads();
        const float M = fmaxf(red[0], red[1]);
        if (w < 2)
            pbuf[tid] = (_Float16)__expf(lq + sv - M);
        __syncthreads();

        // --- phase B: matvec partials; wave w covers enters 32w..32w+32 ---
        float q0 = 0.f, q1 = 0.f;
        #pragma unroll
        for (int kk = 0; kk < 4; ++kk) {
            const float4 wv = *(const float4*)&pbuf[(4 * w + kk) * 8];
            q0 = dot8(P[2 * kk + 0], wv, q0);
            q1 = dot8(P[2 * kk + 1], wv, q1);
        }
        float2 qq; qq.x = q0; qq.y = q1;
        *(float2*)&part[w][2 * lane] = qq;
        __syncthreads();

        // --- phase C: combine, log, emit, advance state ---
        if (tid < KDIM) {
            const float q = part[0][tid] + part[1][tid]
                          + part[2][tid] + part[3][tid];
            const float lg = __logf(q);
            aeb[(size_t)(c + 1) * KDIM + tid] = L + M + lg;
            lq = lg;
            L += M;
        }

        // --- issue group G(c+3) into the just-consumed buffer ---
        if (c + 3 < NMAT) {
            #pragma unroll
            for (int i = 0; i < 8; ++i)
                P[i] = gload16_asm(&Pb[(size_t)(c + 3) * 16384
                                       + ((8 * w + i) * 64 + lane) * 8]);
            sv = gload4_asm(&svb[(size_t)(c + 3) * KDIM + jsv]);
        }
    };

    for (int c = 0; c < NMAT; c += 3) {
        STEP(PA, svA, c);
        if (c + 1 < NMAT) STEP(PB, svB, c + 1);
        if (c + 2 < NMAT) STEP(PC, svC, c + 2);
    }
}

// ============ kernel 3: replay, fallback-structured (R7-R9 proven) ============
__global__ __launch_bounds__(256, 2) void crf_replay3(
    const float* __restrict__ trans, const float* __restrict__ em,
    const int* __restrict__ seq_lens, const float* __restrict__ aEnter,
    float* __restrict__ alpha, float* __restrict__ logZ)
{
    const int c = blockIdx.x, b = blockIdx.y;
    const int tid = threadIdx.x;
    const int j = tid & 127, h = tid >> 7;
    const int lane = tid & 63;

    __shared__ __align__(16) float p_lds[KDIM];
    __shared__ float part[2][KDIM];
    __shared__ float red[8];

    float Ereg[64];
    #pragma unroll
    for (int k = 0; k < 64; ++k)
        Ereg[k] = __expf(trans[(h * 64 + k) * KDIM + j]);

    const int len = seq_lens[b];
    const float* emb = em + (size_t)b * TLEN * KDIM;
    float* outb = alpha + (size_t)b * TLEN * KDIM;

    float a0;
    if (c == 0) a0 = emb[j];
    else        a0 = aEnter[((size_t)b * NCH + c) * KDIM + j];

    {
        float v = a0;
        #pragma unroll
        for (int o = 32; o; o >>= 1) v = fmaxf(v, __shfl_xor(v, o));
        if (lane == 0) red[tid >> 6] = v;
    }
    __syncthreads();
    float L = fmaxf(red[0], red[1]);

    if (h == 0) p_lds[j] = __expf(a0 - L);
    float la = -INFINITY;
    if (c == 0 && h == 0) {
        outb[j] = a0;
        if (len == 1) la = a0;
    }

    const int t_begin = c * CH_L + 1;
    const int t_end = (c == NCH - 1) ? (TLEN - 1) : (c * CH_L + CH_L);

    float ecur = 0.f;
    if (h == 0) ecur = emb[t_begin * KDIM + j];
    __syncthreads();

    for (int t = t_begin; t <= t_end; ++t) {
        float enxt = 0.f;
        if (h == 0 && t < t_end) enxt = emb[(t + 1) * KDIM + j];

        float acc0 = 0.f, acc1 = 0.f, acc2 = 0.f, acc3 = 0.f;
        const float4* p4 = (const float4*)(p_lds + h * 64);
        #pragma unroll
        for (int k4 = 0; k4 < 16; ++k4) {
            const float4 pv = p4[k4];
            acc0 = fmaf(pv.x, Ereg[4 * k4 + 0], acc0);
            acc1 = fmaf(pv.y, Ereg[4 * k4 + 1], acc1);
            acc2 = fmaf(pv.z, Ereg[4 * k4 + 2], acc2);
            acc3 = fmaf(pv.w, Ereg[4 * k4 + 3], acc3);
        }
        part[h][j] = (acc0 + acc1) + (acc2 + acc3);
        __syncthreads();

        if (h == 0) {
            const float q = part[0][j] + part[1][j];
            const float sig = part[0][0] + part[1][0];
            const float A = ecur + L + __logf(q);
            outb[t * KDIM + j] = A;
            if (t == len - 1) la = A;
            p_lds[j] = q * __builtin_amdgcn_rcpf(sig) * __expf(ecur);
            L += __logf(sig);
        }
        ecur = enxt;
        __syncthreads();
    }

    const int xown = (len == 1) ? 0 : ((len - 2) >> 4);
    if (c == xown) {
        float m2 = la;
        #pragma unroll
        for (int o = 32; o; o >>= 1) m2 = fmaxf(m2, __shfl_xor(m2, o));
        if (lane == 0) red[tid >> 6] = m2;
        __syncthreads();
        m2 = fmaxf(fmaxf(red[0], red[1]), fmaxf(red[2], red[3]));
        float e = (la == -INFINITY) ? 0.f : __expf(la - m2);
        #pragma unroll
        for (int o = 32; o; o >>= 1) e += __shfl_xor(e, o);
        if (lane == 0) red[4 + (tid >> 6)] = e;
        __syncthreads();
        if (tid == 0)
            logZ[b] = m2 + __logf(red[4] + red[5] + red[6] + red[7]);
    }
}

// ================= fallback (proven R1 kernel) for small ws =================
__global__ __launch_bounds__(256) void crf_forward_fallback(
    const float* __restrict__ trans, const float* __restrict__ em,
    const int* __restrict__ seq_lens, float* __restrict__ alpha_out,
    float* __restrict__ logZ_out)
{
    const int b = blockIdx.x;
    const int tid = threadIdx.x;
    const int j = tid & (KDIM - 1);
    const int h = tid >> 7;

    __shared__ __align__(16) float p_lds[KDIM];
    __shared__ float part[KDIM];
    __shared__ float red[8];

    float Ereg[64];
    #pragma unroll
    for (int k = 0; k < 64; ++k) Ereg[k] = __expf(trans[(h * 64 + k) * KDIM + j]);

    const int len = seq_lens[b];
    const float* emb = em + (size_t)b * TLEN * KDIM;
    float* outb = alpha_out + (size_t)b * TLEN * KDIM;

    float a = 0.f, last_a = 0.f;
    if (h == 0) {
        a = emb[j];
        outb[j] = a;
        if (len == 1) last_a = a;
    }
    for (int t = 1; t < TLEN; ++t) {
        {
            float v = (h == 0) ? a : -INFINITY;
            #pragma unroll
            for (int o = 32; o >= 1; o >>= 1) v = fmaxf(v, __shfl_xor(v, o));
            if ((tid & 63) == 0) red[tid >> 6] = v;
        }
        __syncthreads();
        const float m = fmaxf(red[0], red[1]);
        if (h == 0) p_lds[j] = __expf(a - m);
        __syncthreads();
        float em_t = 0.f;
        if (h == 0) em_t = emb[t * KDIM + j];
        float acc0 = 0.f, acc1 = 0.f, acc2 = 0.f, acc3 = 0.f;
        const float4* p4 = (const float4*)(p_lds + h * 64);
        #pragma unroll
        for (int k4 = 0; k4 < 16; ++k4) {
            float4 pv = p4[k4];
            acc0 = fmaf(pv.x, Ereg[4 * k4 + 0], acc0);
            acc1 = fmaf(pv.y, Ereg[4 * k4 + 1], acc1);
            acc2 = fmaf(pv.z, Ereg[4 * k4 + 2], acc2);
            acc3 = fmaf(pv.w, Ereg[4 * k4 + 3], acc3);
        }
        const float acc = (acc0 + acc1) + (acc2 + acc3);
        if (h == 1) part[j] = acc;
        __syncthreads();
        if (h == 0) {
            const float q = acc + part[j];
            a = em_t + m + __logf(q);
            outb[t * KDIM + j] = a;
            if (t == len - 1) last_a = a;
        }
    }
    {
        float v = (h == 0) ? last_a : -INFINITY;
        #pragma unroll
        for (int o = 32; o >= 1; o >>= 1) v = fmaxf(v, __shfl_xor(v, o));
        if ((tid & 63) == 0) red[tid >> 6] = v;
    }
    __syncthreads();
    const float m2 = fmaxf(red[0], red[1]);
    float e = (h == 0) ? __expf(last_a - m2) : 0.f;
    #pragma unroll
    for (int o = 32; o >= 1; o >>= 1) e += __shfl_xor(e, o);
    if ((tid & 63) == 0) red[4 + (tid >> 6)] = e;
    __syncthreads();
    if (tid == 0) logZ_out[b] = m2 + logf(red[4] + red[5]);
}

extern "C" void kernel_launch(void* const* d_in, const int* in_sizes, int n_in,
                              void* d_out, int out_size, void* d_ws, size_t ws_size,
                              hipStream_t stream) {
    const float* trans    = (const float*)d_in[0];   // K*K
    const float* em       = (const float*)d_in[1];   // B*T*K
    const int*   seq_lens = (const int*)d_in[2];     // B

    float* alpha_out = (float*)d_out;                            // B*T*K
    float* logZ_out  = alpha_out + (size_t)BATCH * TLEN * KDIM;  // B

    char* ws = (char*)d_ws;

    if (ws_size >= (size_t)WSN_NEED) {
        _Float16* Pst  = (_Float16*)(ws + WSN_PST);
        float*    Svec = (float*)(ws + WSN_SVEC);
        float*    aEnt = (float*)(ws + WSN_AENT);
        crf_chunkcols6<<<NMAT * BATCH, 256, 0, stream>>>(trans, em, Pst, Svec);
        crf_scanw9<<<BATCH, 256, 0, stream>>>(em, Pst, Svec, aEnt);
        crf_replay3<<<dim3(NCH, BATCH), 256, 0, stream>>>(trans, em, seq_lens, aEnt,
                                                          alpha_out, logZ_out);
    } else {
        crf_forward_fallback<<<BATCH, 256, 0, stream>>>(trans, em, seq_lens,
                                                        alpha_out, logZ_out);
    }
}